// Round 6
// baseline (441.311 us; speedup 1.0000x reference)
//
#include <hip/hip_runtime.h>

typedef _Float16 f16;
typedef __attribute__((ext_vector_type(8))) _Float16 f16x8;
typedef __attribute__((ext_vector_type(4))) _Float16 f16x4;
typedef __attribute__((ext_vector_type(4))) float    f32x4;

#define MFMA(a,b,c) __builtin_amdgcn_mfma_f32_16x16x32_f16(a,b,c,0,0,0)

// problem constants
constexpr int Bc = 2, Nc = 65536, Cc = 256, Hc = 8;
constexpr int CHUNK = 512;                 // tokens per block: 4 m0-tiles of 128
constexpr int LDXX = 264;                  // X-resident stride (f16): 528B rows, 16B-aligned
constexpr int LDT  = 136;                  // transpose stride (f16): 272B rows, 16B-aligned
// Rounds 2/3 lesson: any LDS row stride that puts ds_*_b128 off 16B alignment
// costs 2.3x (201->473 µs) with ZERO bank conflicts. Alignment first.

// ---- workspace layout (bytes) ----
// 0      : Tg    float[16*4096] (262144)
// 262144 : normg float[16*64]   (4096)
// 266240 : WC    f16[8*128*256] (524288)  [h][n][k]; n 0..63 = Wfx cols, 64..127 = Wxs
// 790528 : bsp   float[8*64]    (2048)

__device__ __forceinline__ f32x4 splat4(float v) { f32x4 r; r.x=v; r.y=v; r.z=v; r.w=v; return r; }
__device__ __forceinline__ f16x8 pack8(float4 a, float4 b) {
  f16x8 r = { (f16)a.x,(f16)a.y,(f16)a.z,(f16)a.w,(f16)b.x,(f16)b.y,(f16)b.z,(f16)b.w };
  return r;
}
__device__ __forceinline__ void gl_lds16(const f16* g, f16* l) {
  __builtin_amdgcn_global_load_lds((const __attribute__((address_space(1))) void*)g,
                                   (__attribute__((address_space(3))) void*)l, 16, 0, 0);
}
// combined barrier: drain everything, sync, pin scheduler (rule-18 fence)
__device__ __forceinline__ void bar_all() {
  asm volatile("s_waitcnt vmcnt(0) lgkmcnt(0)" ::: "memory");
  __builtin_amdgcn_s_barrier();
  __builtin_amdgcn_sched_barrier(0);
}
__device__ __forceinline__ void bar_lgkm() {
  asm volatile("s_waitcnt lgkmcnt(0)" ::: "memory");
  __builtin_amdgcn_s_barrier();
  __builtin_amdgcn_sched_barrier(0);
}

// prep: 162 blocks. b<32: Wfx transpose; 32<=b<96: Wxs; b==96: bsp;
// 97<=b<162: zero Tg+normg.
__global__ void prep_a(const float* __restrict__ Wx, const float* __restrict__ Wfx,
                       const float* __restrict__ Wsl, const float* __restrict__ bx,
                       const float* __restrict__ bsl, f16* __restrict__ WC,
                       float* __restrict__ bsp, float* __restrict__ Tz) {
  __shared__ float tile[64][72];
  const int b = blockIdx.x, t = threadIdx.x;
  if (b < 32) {
    const int k0 = (b & 3) * 64, c0 = (b >> 2) * 64;
    const int r = t >> 4, c4 = (t & 15) * 4;
    #pragma unroll
    for (int i = 0; i < 4; ++i) {
      float4 v = *(const float4*)&Wfx[(size_t)(k0 + r + i*16)*512 + c0 + c4];
      tile[r + i*16][c4] = v.x; tile[r + i*16][c4+1] = v.y;
      tile[r + i*16][c4+2] = v.z; tile[r + i*16][c4+3] = v.w;
    }
    __syncthreads();
    const int cl = t >> 2, kq = t & 3;
    const int col = c0 + cl, h = col >> 6, n = col & 63;
    f16 tmp[16];
    #pragma unroll
    for (int j = 0; j < 16; ++j) tmp[j] = (f16)tile[kq*16 + j][cl];
    f16* dst = WC + (size_t)(h*128 + n)*256 + k0 + kq*16;
    *(f16x8*)dst       = *(f16x8*)&tmp[0];
    *(f16x8*)(dst + 8) = *(f16x8*)&tmp[8];
  } else if (b < 96) {
    const int bb = b - 32;
    const int h = bb >> 3, k0 = (bb & 7) * 32;
    const int k = t & 31, sq = t >> 5;
    float accs[8];
    #pragma unroll
    for (int j = 0; j < 8; ++j) accs[j] = 0.f;
    for (int d = 0; d < 64; ++d) {
      float a = Wx[(size_t)(k0 + k)*512 + h*64 + d];
      #pragma unroll
      for (int j = 0; j < 8; ++j) accs[j] += a * Wsl[d*64 + sq*8 + j];
    }
    #pragma unroll
    for (int j = 0; j < 8; ++j)
      WC[(size_t)(h*128 + 64 + sq*8 + j)*256 + k0 + k] = (f16)accs[j];
  } else if (b == 96) {
    for (int u = t; u < 512; u += 256) {
      int h = u >> 6, s = u & 63;
      float a = bsl[s];
      for (int d = 0; d < 64; ++d) a += bx[h*64 + d] * Wsl[d*64 + s];
      bsp[h*64 + s] = a;
    }
  } else {
    float4 z; z.x = z.y = z.z = z.w = 0.f;
    ((float4*)Tz)[(b - 97) * 256 + t] = z;
  }
}

// All-heads-per-block: grid 256 (one block per 512-token chunk, one per CU).
// Per m0: stage X[128][256] f16 ONCE (reg+pack; was done 8x in the per-head
// grid — the dominant redundant VALU+DS work). W[h][128][64] panels stream via
// global_load_lds double-buffer (zero wave-issue cost), linear layout + r5's
// verified both-sides XOR swizzle (source slot (l&7)^(l>>3), read addr
// ^((ln&7)*8)). One combined vmcnt(0)+lgkm(0) barrier per kb-step; W(kb+1)
// DMA issued right after it gets the whole MFMA phase to land (L2-hot).
// No LDS aliasing: X 66K | W dbuf 32K | fxT/wT 34K = 133 KiB -> 1 block/CU
// (r5 measured 1-block/CU costs only ~5% vs 2 — redundancy removal dwarfs it).
// Epilogue / Phase C / flush byte-identical to the 201-µs r4 kernel per head;
// K-accumulation order unchanged -> same absmax.
__global__ __launch_bounds__(256, 1)
void fused_all(const float* __restrict__ x,   const float* __restrict__ bfx,
               const float* __restrict__ bsp, const float* __restrict__ temp,
               const f16* __restrict__ WC,    float* __restrict__ Tg,
               float* __restrict__ normg) {
  __shared__ alignas(1024) char smem[136192];
  f16* X      = (f16*)smem;                  // [128][LDXX]  (67584 B)
  f16* W0     = (f16*)(smem + 68608);        // [128][64]    (16384 B)
  f16* W1     = (f16*)(smem + 84992);        // [128][64]    (16384 B)
  f16* sm_fxT = (f16*)(smem + 101376);       // [64][LDT]    (17408 B)
  f16* sm_wT  = (f16*)(smem + 118784);       // [64][LDT]    (17408 B)

  const int chunk = blockIdx.x;              // 256 blocks, 1 per CU
  const long tokBase = (long)chunk * CHUNK;
  const int b = (int)(tokBase >> 16);

  const int tid = threadIdx.x;
  const int wv = tid >> 6, lane = tid & 63, quad = lane >> 4, ln = lane & 15;
  const int wm = wv >> 1, wn = wv & 1;
  const int ci = wv >> 1, cj = wv & 1;
  const int r0 = tid >> 2, seg = tid & 3;
  const int l8 = lane >> 3, sl = (lane & 7) ^ l8;
  const int swl = (ln & 7) * 8;              // W-tile read swizzle

  // stage one W panel tile [128 n][64 k] of head h, k-block kb, into buf p.
  // 4 DMA instrs/wave; wave wv covers rows wv*32..wv*32+31.
  auto stageW = [&](int h, int kb, int p) {
    f16* dst = (p ? W1 : W0) + wv * 2048;
    const f16* src = WC + ((size_t)(h*128 + wv*32 + l8))*256 + kb*64 + sl*8;
    #pragma unroll
    for (int i = 0; i < 4; ++i)
      gl_lds16(src + i*(8*256), dst + i*512);
  };

  // stage X m0-tile [128 tok][256 k] f32 -> f16, once per m0 (not per head).
  auto stageX = [&](int m0) {
    const float* p = x + (tokBase + (long)m0*128 + r0)*Cc + seg*16;
    #pragma unroll
    for (int kb = 0; kb < 4; ++kb) {
      const float* q  = p + kb*64;
      const float* q2 = q + 64*Cc;
      float4 a0 = *(const float4*)q,      a1 = *(const float4*)(q+4);
      float4 a2 = *(const float4*)(q+8),  a3 = *(const float4*)(q+12);
      float4 b0 = *(const float4*)q2,     b1 = *(const float4*)(q2+4);
      float4 b2 = *(const float4*)(q2+8), b3 = *(const float4*)(q2+12);
      *(f16x8*)&X[r0*LDXX + kb*64 + seg*16]          = pack8(a0, a1);
      *(f16x8*)&X[r0*LDXX + kb*64 + seg*16 + 8]      = pack8(a2, a3);
      *(f16x8*)&X[(r0+64)*LDXX + kb*64 + seg*16]     = pack8(b0, b1);
      *(f16x8*)&X[(r0+64)*LDXX + kb*64 + seg*16 + 8] = pack8(b2, b3);
    }
  };

  #pragma unroll 1
  for (int m0 = 0; m0 < 4; ++m0) {
    // X readers (prev m0 head7 kb3) retired before prev PhaseC-top barrier;
    // W0's last readers (prev u=30/kb2) retired before u=31's top barrier.
    stageX(m0);
    stageW(0, 0, 0);

    #pragma unroll 1
    for (int h = 0; h < 8; ++h) {
      const float tc = fminf(fmaxf(temp[h], 0.5f), 5.0f);
      const float k2 = 1.44269504f / tc;
      float bv[4];
      {
        const float* bb = (wn == 0) ? (bfx + h*64) : (bsp + h*64);
        #pragma unroll
        for (int nt = 0; nt < 4; ++nt) bv[nt] = bb[nt*16 + ln];
      }

      f32x4 acc[4][4];
      #pragma unroll
      for (int mt = 0; mt < 4; ++mt)
        #pragma unroll
        for (int nt = 0; nt < 4; ++nt) acc[mt][nt] = splat4(bv[nt]);

      #pragma unroll
      for (int kb = 0; kb < 4; ++kb) {
        // top barrier: W(h,kb) DMA landed (all waves), prev-step frag reads
        // retired (lgkm), X/fxT writes visible where applicable.
        bar_all();
        // prefetch next W tile into the other buffer (readers retired 2 steps
        // ago, certified by the previous top barriers)
        if (kb < 3)       stageW(h, kb + 1, (kb + 1) & 1);
        else if (h < 7)   stageW(h + 1, 0, 0);
        const f16* Wb = (kb & 1) ? W1 : W0;
        #pragma unroll
        for (int ks = 0; ks < 2; ++ks) {
          f16x8 af[4], bf[4];
          #pragma unroll
          for (int mt = 0; mt < 4; ++mt)
            af[mt] = *(const f16x8*)&X[(wm*64 + mt*16 + ln)*LDXX + kb*64 + ks*32 + quad*8];
          #pragma unroll
          for (int nt = 0; nt < 4; ++nt)
            bf[nt] = *(const f16x8*)&Wb[(wn*64 + nt*16 + ln)*64 + ((ks*32 + quad*8) ^ swl)];
          #pragma unroll
          for (int mt = 0; mt < 4; ++mt)
            #pragma unroll
            for (int nt = 0; nt < 4; ++nt)
              acc[mt][nt] = MFMA(af[mt], bf[nt], acc[mt][nt]);
        }
      }
      // no barrier needed: fxT/wT's previous readers (head h-1 PhaseC) retired
      // before this head's kb0 top barrier; no region conflict with W bufs.

      // ---------- epilogue (identical math to r4) ----------
      if (wn == 0) {
        #pragma unroll
        for (int mt = 0; mt < 4; ++mt)
          #pragma unroll
          for (int nt = 0; nt < 4; ++nt) {
            f16x4 v = { (f16)acc[mt][nt][0], (f16)acc[mt][nt][1],
                        (f16)acc[mt][nt][2], (f16)acc[mt][nt][3] };
            *(f16x4*)&sm_fxT[(nt*16 + ln)*LDT + wm*64 + mt*16 + quad*4] = v;
          }
      } else {
        #pragma unroll
        for (int mt = 0; mt < 4; ++mt) {
          float e[4][4], wout[4][4];
          #pragma unroll
          for (int nt = 0; nt < 4; ++nt)
            #pragma unroll
            for (int rg = 0; rg < 4; ++rg)
              e[nt][rg] = exp2f(acc[mt][nt][rg] * k2);   // logits bounded
          #pragma unroll
          for (int rg = 0; rg < 4; ++rg) {
            float rs = e[0][rg] + e[1][rg] + e[2][rg] + e[3][rg];
            #pragma unroll
            for (int dd = 1; dd < 16; dd <<= 1) rs += __shfl_xor(rs, dd, 64);
            float inv = 1.0f / rs;
            #pragma unroll
            for (int nt = 0; nt < 4; ++nt) {
              wout[nt][rg] = e[nt][rg] * inv;
            }
          }
          #pragma unroll
          for (int nt = 0; nt < 4; ++nt) {
            f16x4 v = { (f16)wout[nt][0], (f16)wout[nt][1],
                        (f16)wout[nt][2], (f16)wout[nt][3] };
            *(f16x4*)&sm_wT[(nt*16 + ln)*LDT + wm*64 + mt*16 + quad*4] = v;
          }
        }
      }
      bar_lgkm();                            // epilogue writes visible

      // ---------- Phase C: T[s][d] += w^T @ fx, K=128 ----------
      f32x4 Tacc[2][2];
      #pragma unroll
      for (int i = 0; i < 2; ++i) { Tacc[i][0] = splat4(0.f); Tacc[i][1] = splat4(0.f); }
      float nacc[4] = {0.f, 0.f, 0.f, 0.f};
      #pragma unroll
      for (int ks = 0; ks < 4; ++ks) {
        f16x8 a0 = *(const f16x8*)&sm_wT [(ci*32 +      ln)*LDT + ks*32 + quad*8];
        f16x8 a1 = *(const f16x8*)&sm_wT [(ci*32 + 16 + ln)*LDT + ks*32 + quad*8];
        f16x8 b0 = *(const f16x8*)&sm_fxT[(cj*32 +      ln)*LDT + ks*32 + quad*8];
        f16x8 b1 = *(const f16x8*)&sm_fxT[(cj*32 + 16 + ln)*LDT + ks*32 + quad*8];
        Tacc[0][0] = MFMA(a0, b0, Tacc[0][0]);
        Tacc[0][1] = MFMA(a0, b1, Tacc[0][1]);
        Tacc[1][0] = MFMA(a1, b0, Tacc[1][0]);
        Tacc[1][1] = MFMA(a1, b1, Tacc[1][1]);
      }
      // norm accumulation: recompute from wT is wrong (it's f16-rounded);
      // use the same wout sums as r4: wn==1 waves hold them — but Tacc/nacc
      // were per-block-life in r4. Here per-head: sum wT columns via the
      // MFMA-free path is unnecessary — recover nacc from the epilogue pass:
      // (r4 accumulated nacc inside the epilogue; do the same here.)
      // NOTE: nacc handled below via the epilogue-computed values.
      // ---------- flush head h ----------
      {
        const int bh = b * Hc + h;
        float* Tb = Tg + bh * 4096;
        #pragma unroll
        for (int mt2 = 0; mt2 < 2; ++mt2)
          #pragma unroll
          for (int nt2 = 0; nt2 < 2; ++nt2)
            #pragma unroll
            for (int rg = 0; rg < 4; ++rg) {
              int s = ci*32 + mt2*16 + quad*4 + rg;
              int d = cj*32 + nt2*16 + ln;
              atomicAdd(&Tb[s*64 + d], Tacc[mt2][nt2][rg]);
            }
        // norm: sum of softmax weights over this head's 128 tokens.
        // wT[s][tok] holds the f16 weights; but r4 summed the f32 wout values
        // BEFORE f16 rounding. To preserve numerics exactly, wn==1 waves
        // recompute the sums from their wout registers is no longer possible
        // (scope ended) — so nacc is accumulated in the epilogue loop below.
        (void)nacc;
      }
    }
  }
}

// nacc accumulation was folded back into the epilogue in the kernel above via
// a second pass; to keep numerics identical to r4 (f32 wout sums) we instead
// run a small dedicated kernel: norm[bh][s] = sum_n w[bh][n][s] computed from
// the same f32 pipeline. Simpler and exact: recompute inside fused_all's
// epilogue. See fused_all2 below — the actually-launched kernel.

// The launched kernel: same as fused_all but with nacc accumulated in the
// epilogue (wn==1 waves) and flushed per head, matching r4's numerics.
__global__ __launch_bounds__(256, 1)
void fused_all2(const float* __restrict__ x,   const float* __restrict__ bfx,
                const float* __restrict__ bsp, const float* __restrict__ temp,
                const f16* __restrict__ WC,    float* __restrict__ Tg,
                float* __restrict__ normg) {
  __shared__ alignas(1024) char smem[136192];
  f16* X      = (f16*)smem;
  f16* W0     = (f16*)(smem + 68608);
  f16* W1     = (f16*)(smem + 84992);
  f16* sm_fxT = (f16*)(smem + 101376);
  f16* sm_wT  = (f16*)(smem + 118784);

  const int chunk = blockIdx.x;
  const long tokBase = (long)chunk * CHUNK;
  const int b = (int)(tokBase >> 16);

  const int tid = threadIdx.x;
  const int wv = tid >> 6, lane = tid & 63, quad = lane >> 4, ln = lane & 15;
  const int wm = wv >> 1, wn = wv & 1;
  const int ci = wv >> 1, cj = wv & 1;
  const int r0 = tid >> 2, seg = tid & 3;
  const int l8 = lane >> 3, sl = (lane & 7) ^ l8;
  const int swl = (ln & 7) * 8;

  auto stageW = [&](int h, int kb, int p) {
    f16* dst = (p ? W1 : W0) + wv * 2048;
    const f16* src = WC + ((size_t)(h*128 + wv*32 + l8))*256 + kb*64 + sl*8;
    #pragma unroll
    for (int i = 0; i < 4; ++i)
      gl_lds16(src + i*(8*256), dst + i*512);
  };
  auto stageX = [&](int m0) {
    const float* p = x + (tokBase + (long)m0*128 + r0)*Cc + seg*16;
    #pragma unroll
    for (int kb = 0; kb < 4; ++kb) {
      const float* q  = p + kb*64;
      const float* q2 = q + 64*Cc;
      float4 a0 = *(const float4*)q,      a1 = *(const float4*)(q+4);
      float4 a2 = *(const float4*)(q+8),  a3 = *(const float4*)(q+12);
      float4 b0 = *(const float4*)q2,     b1 = *(const float4*)(q2+4);
      float4 b2 = *(const float4*)(q2+8), b3 = *(const float4*)(q2+12);
      *(f16x8*)&X[r0*LDXX + kb*64 + seg*16]          = pack8(a0, a1);
      *(f16x8*)&X[r0*LDXX + kb*64 + seg*16 + 8]      = pack8(a2, a3);
      *(f16x8*)&X[(r0+64)*LDXX + kb*64 + seg*16]     = pack8(b0, b1);
      *(f16x8*)&X[(r0+64)*LDXX + kb*64 + seg*16 + 8] = pack8(b2, b3);
    }
  };

  #pragma unroll 1
  for (int m0 = 0; m0 < 4; ++m0) {
    stageX(m0);
    stageW(0, 0, 0);

    #pragma unroll 1
    for (int h = 0; h < 8; ++h) {
      const float tc = fminf(fmaxf(temp[h], 0.5f), 5.0f);
      const float k2 = 1.44269504f / tc;
      float bv[4];
      {
        const float* bb = (wn == 0) ? (bfx + h*64) : (bsp + h*64);
        #pragma unroll
        for (int nt = 0; nt < 4; ++nt) bv[nt] = bb[nt*16 + ln];
      }

      f32x4 acc[4][4];
      #pragma unroll
      for (int mt = 0; mt < 4; ++mt)
        #pragma unroll
        for (int nt = 0; nt < 4; ++nt) acc[mt][nt] = splat4(bv[nt]);

      #pragma unroll
      for (int kb = 0; kb < 4; ++kb) {
        bar_all();
        if (kb < 3)      stageW(h, kb + 1, (kb + 1) & 1);
        else if (h < 7)  stageW(h + 1, 0, 0);
        const f16* Wb = (kb & 1) ? W1 : W0;
        #pragma unroll
        for (int ks = 0; ks < 2; ++ks) {
          f16x8 af[4], bf[4];
          #pragma unroll
          for (int mt = 0; mt < 4; ++mt)
            af[mt] = *(const f16x8*)&X[(wm*64 + mt*16 + ln)*LDXX + kb*64 + ks*32 + quad*8];
          #pragma unroll
          for (int nt = 0; nt < 4; ++nt)
            bf[nt] = *(const f16x8*)&Wb[(wn*64 + nt*16 + ln)*64 + ((ks*32 + quad*8) ^ swl)];
          #pragma unroll
          for (int mt = 0; mt < 4; ++mt)
            #pragma unroll
            for (int nt = 0; nt < 4; ++nt)
              acc[mt][nt] = MFMA(af[mt], bf[nt], acc[mt][nt]);
        }
      }

      float nacc[4] = {0.f, 0.f, 0.f, 0.f};
      if (wn == 0) {
        #pragma unroll
        for (int mt = 0; mt < 4; ++mt)
          #pragma unroll
          for (int nt = 0; nt < 4; ++nt) {
            f16x4 v = { (f16)acc[mt][nt][0], (f16)acc[mt][nt][1],
                        (f16)acc[mt][nt][2], (f16)acc[mt][nt][3] };
            *(f16x4*)&sm_fxT[(nt*16 + ln)*LDT + wm*64 + mt*16 + quad*4] = v;
          }
      } else {
        #pragma unroll
        for (int mt = 0; mt < 4; ++mt) {
          float e[4][4], wout[4][4];
          #pragma unroll
          for (int nt = 0; nt < 4; ++nt)
            #pragma unroll
            for (int rg = 0; rg < 4; ++rg)
              e[nt][rg] = exp2f(acc[mt][nt][rg] * k2);
          #pragma unroll
          for (int rg = 0; rg < 4; ++rg) {
            float rs = e[0][rg] + e[1][rg] + e[2][rg] + e[3][rg];
            #pragma unroll
            for (int dd = 1; dd < 16; dd <<= 1) rs += __shfl_xor(rs, dd, 64);
            float inv = 1.0f / rs;
            #pragma unroll
            for (int nt = 0; nt < 4; ++nt) {
              wout[nt][rg] = e[nt][rg] * inv;
              nacc[nt] += wout[nt][rg];
            }
          }
          #pragma unroll
          for (int nt = 0; nt < 4; ++nt) {
            f16x4 v = { (f16)wout[nt][0], (f16)wout[nt][1],
                        (f16)wout[nt][2], (f16)wout[nt][3] };
            *(f16x4*)&sm_wT[(nt*16 + ln)*LDT + wm*64 + mt*16 + quad*4] = v;
          }
        }
      }
      bar_lgkm();

      f32x4 Tacc[2][2];
      #pragma unroll
      for (int i = 0; i < 2; ++i) { Tacc[i][0] = splat4(0.f); Tacc[i][1] = splat4(0.f); }
      #pragma unroll
      for (int ks = 0; ks < 4; ++ks) {
        f16x8 a0 = *(const f16x8*)&sm_wT [(ci*32 +      ln)*LDT + ks*32 + quad*8];
        f16x8 a1 = *(const f16x8*)&sm_wT [(ci*32 + 16 + ln)*LDT + ks*32 + quad*8];
        f16x8 b0 = *(const f16x8*)&sm_fxT[(cj*32 +      ln)*LDT + ks*32 + quad*8];
        f16x8 b1 = *(const f16x8*)&sm_fxT[(cj*32 + 16 + ln)*LDT + ks*32 + quad*8];
        Tacc[0][0] = MFMA(a0, b0, Tacc[0][0]);
        Tacc[0][1] = MFMA(a0, b1, Tacc[0][1]);
        Tacc[1][0] = MFMA(a1, b0, Tacc[1][0]);
        Tacc[1][1] = MFMA(a1, b1, Tacc[1][1]);
      }

      const int bh = b * Hc + h;
      float* Tb = Tg + bh * 4096;
      #pragma unroll
      for (int mt2 = 0; mt2 < 2; ++mt2)
        #pragma unroll
        for (int nt2 = 0; nt2 < 2; ++nt2)
          #pragma unroll
          for (int rg = 0; rg < 4; ++rg) {
            int s = ci*32 + mt2*16 + quad*4 + rg;
            int d = cj*32 + nt2*16 + ln;
            atomicAdd(&Tb[s*64 + d], Tacc[mt2][nt2][rg]);
          }
      if (wn == 1) {
        #pragma unroll
        for (int nt = 0; nt < 4; ++nt) {
          float v = nacc[nt];
          v += __shfl_xor(v, 16, 64);
          v += __shfl_xor(v, 32, 64);
          if (lane < 16) atomicAdd(&normg[bh*64 + nt*16 + ln], v);
        }
      }
    }
  }
}

__global__ void finalize(const float* __restrict__ Tg, const float* __restrict__ normg,
                         float* __restrict__ out) {
  int i = blockIdx.x * 256 + threadIdx.x;
  out[i] = Tg[i] / (normg[i >> 6] + 0.01f);
}

extern "C" void kernel_launch(void* const* d_in, const int* in_sizes, int n_in,
                              void* d_out, int out_size, void* d_ws, size_t ws_size,
                              hipStream_t stream) {
  const float* x    = (const float*)d_in[0];
  const float* Wx   = (const float*)d_in[1];
  const float* bx   = (const float*)d_in[2];
  const float* Wfx  = (const float*)d_in[3];
  const float* bfx  = (const float*)d_in[4];
  const float* Wsl  = (const float*)d_in[5];
  const float* bsl  = (const float*)d_in[6];
  const float* temp = (const float*)d_in[7];
  float* out = (float*)d_out;

  float* Tg    = (float*)d_ws;
  float* normg = Tg + 16 * 4096;
  f16*   WC    = (f16*)((char*)d_ws + 266240);
  float* bsp   = (float*)((char*)d_ws + 790528);

  prep_a    <<<162, 256, 0, stream>>>(Wx, Wfx, Wsl, bx, bsl, WC, bsp, Tg);
  fused_all2<<<256, 256, 0, stream>>>(x, bfx, bsp, temp, WC, Tg, normg);
  finalize  <<<256, 256, 0, stream>>>(Tg, normg, out);
}